// Round 9
// baseline (136.788 us; speedup 1.0000x reference)
//
#include <hip/hip_runtime.h>

// CatNet_76553497084407 — SLAYER-style spiking CNN, fully collapsed over time.
//
// R16 = R13/R15 (best, ~99us bench, kernel ~35us, absmax 0.0) + weights moved
// from s_load (SMEM) to uniform-address VMEM float4 loads in phases 2/4.
//
// Why: SMEM shares lgkmcnt with ds_read and completes OUT OF ORDER, so every
// weight use forces s_waitcnt lgkmcnt(0), draining tap reads/prefetch -> R15's
// tap prefetch was provably null, and the conv loops serialize on every
// weight batch. VMEM weights wait on vmcnt instead: independent counter, taps
// pipeline on lgkmcnt, 4 waves/SIMD cover the L1-hit weight latency (weights
// are 18KB total -> L1-resident after first pass).
//   * w2[j][qd*4..+3][0..8] = 36 contiguous 16B-aligned floats = 9 float4;
//     w3[j][q*4..+3][0..6] = 28 floats = 7 float4. Uniform across the wave ->
//     one cache line per load, no R12-style per-lane scatter.
//   * Compiler would re-scalarize a provably-uniform address back to s_load;
//     defeated with an opaque v_mov_b32 0 asm VGPR added to the base.
//   * Accumulation order per output unchanged -> absmax 0.0 expected.
//   * All-16-wave mapping kept (R14: idling waves costs more than DS slots).
//   * DS-slot law intact: DS traffic identical to R13.
// Spill tripwire: WRITE_SIZE must stay ~tens of KB (spills were 190MB+).

#define T_STEPS 50
#define THETA   0.9999f

// component of a float4 by compile-time index (folds after unroll)
#define F4C(v, c) ((c) == 0 ? (v).x : (c) == 1 ? (v).y : (c) == 2 ? (v).z : (v).w)

// Exact-rounding rate: tbl[c] == c/50.0f computed with a true divide once.
__device__ __forceinline__ float spike_rate(float a, const float* __restrict__ tbl) {
    constexpr float INV = 50.0f / 0.9999f;
    float t = a * INV;
    float c = fminf(fmaxf(floorf(t), 0.0f), 50.0f);
    // fall back to the exact 50-step f32 sim when t is near an integer
    bool risky = (t > 0.5f) && (fabsf(t - rintf(t)) < 2e-4f);
    if (__ballot(risky)) {
        float v = 0.f, cnt = 0.f;
#pragma unroll 1
        for (int k = 0; k < T_STEPS; ++k) {
            v += a;
            float s = (v >= THETA) ? 1.0f : 0.0f;
            v -= s * THETA;
            cnt += s;
        }
        c = cnt;
    }
    return tbl[(int)c];
}

// No-ballot variant: only legal when the input provably cannot sit within
// 2e-4 of an integer boundary in t-units (pooled path: 1.1*k/50, margin 1.1e-3).
__device__ __forceinline__ float spike_rate_nb(float a, const float* __restrict__ tbl) {
    constexpr float INV = 50.0f / 0.9999f;
    float t = a * INV;
    float c = fminf(fmaxf(floorf(t), 0.0f), 50.0f);
    return tbl[(int)c];
}

extern "C" __global__ void __launch_bounds__(1024, 4)
catnet_kernel(const float* __restrict__ x,
              const float* __restrict__ w1, const float* __restrict__ b1,
              const float* __restrict__ w2, const float* __restrict__ b2,
              const float* __restrict__ w3, const float* __restrict__ b3,
              const float* __restrict__ wf, const float* __restrict__ bf,
              float* __restrict__ out)
{
    const int n    = blockIdx.x;
    const int tid  = threadIdx.x;
    const int wave = tid >> 6;
    const int lane = tid & 63;

    // opaque zero: forces weight addresses to be VGPR-dependent so the
    // compiler emits global_load (vmcnt) instead of s_load (lgkmcnt).
    int vzero;
    asm volatile("v_mov_b32 %0, 0" : "=v"(vzero));

    __shared__ float  xbar[182];        // [h+1], h in [0,180)
    __shared__ float4 r1qe[4][92];      // [ciq][i] = conv1 rate at even padded H=2i, ci quad
    __shared__ float4 r1qo[4][92];      // [ciq][i] = odd padded H=2i+1
    __shared__ float4 r3q[8][89];       // [ciq][p+1] = pooled rate, ci quad
    __shared__ alignas(16) float r4s[32][83];
    __shared__ float  ratetbl[51];      // exact c/50.0f
    __shared__ float  part[16];

    // zero conv pads + build exact-rate table
    const float4 z4 = make_float4(0.f, 0.f, 0.f, 0.f);
    if (tid < 4)               r1qe[tid][0]       = z4;   // H=0 pad
    if (tid >= 4  && tid < 8)  r1qo[tid - 4][90]  = z4;   // H=181 pad
    if (tid >= 8  && tid < 16) r3q[tid - 8][0]    = z4;   // p_idx=0 pad
    if (tid >= 16 && tid < 24) r3q[tid - 16][88]  = z4;   // p_idx=88 pad
    if (tid == 64)             { xbar[0] = 0.f; xbar[181] = 0.f; }
    if (tid >= 128 && tid < 179) ratetbl[tid - 128] = (float)(tid - 128) / 50.0f;

    // ---- phase 0: time-sum of input, 4 lanes per h, float2 loads ----
    const float* xn = x + (size_t)n * (180 * 50);
    if (tid < 720) {
        const int h = tid >> 2, q = tid & 3;
        const float2* row2 = reinterpret_cast<const float2*>(xn + h * 50);
        float s = 0.f;
        for (int k = q; k < 24; k += 4) { float2 v = row2[k]; s += v.x + v.y; }
        if (q == 0)                     { float2 v = row2[24]; s += v.x + v.y; }
        s += __shfl_xor(s, 1, 4);
        s += __shfl_xor(s, 2, 4);
        if (q == 0) xbar[h + 1] = s;
    }
    __syncthreads();

    // ---- phase 1: conv1 (1->16, k=3, pad=1), /T, +b1, rate ----
    for (int idx = tid; idx < 16 * 180; idx += 1024) {
        int c = idx / 180, h = idx - c * 180;
        float a = w1[c*3+0] * xbar[h] + w1[c*3+1] * xbar[h+1] + w1[c*3+2] * xbar[h+2];
        a = a / 50.0f + b1[c];
        float r = spike_rate(a, ratetbl);
        int H = h + 1;
        float* dst = (H & 1) ? (float*)&r1qo[c >> 2][H >> 1]
                             : (float*)&r1qe[c >> 2][H >> 1];
        dst[c & 3] = r;
    }
    __syncthreads();

    // ---- phase 2: conv2 (16->32, k=9, pad=1) + rate + pool(2)*1.1 + rate ----
    // 8 groups of 128 threads: g = tid>>7 (wave-uniform), p = tid&127 < 87.
    // Thread computes conv2 at h=2p,2p+1 (shared 10-tap window) for 4 out-ch.
    // Taps: 10 ds_read_b128 per ci-quad (lgkmcnt). Weights: per (j,qd) one
    // block of 9 aligned float4 VMEM loads (vmcnt) -> counters decoupled.
    {
        const int g   = __builtin_amdgcn_readfirstlane(tid >> 7);   // 0..7
        const int p   = tid & 127;
        const bool act = p < 87;
        const int pr  = act ? p : 0;
        const float* wbv = w2 + g * 4 * 144 + vzero;   // VGPR-dependent base

        float a0[4], a1[4];
#pragma unroll
        for (int j = 0; j < 4; ++j) { a0[j] = b2[g*4 + j]; a1[j] = a0[j]; }

#pragma unroll 1
        for (int qd = 0; qd < 4; ++qd) {
            float4 we[5], wo[5];
#pragma unroll
            for (int d = 0; d < 5; ++d) { we[d] = r1qe[qd][pr + d]; wo[d] = r1qo[qd][pr + d]; }

#pragma unroll
            for (int j = 0; j < 4; ++j) {
                // 36 contiguous floats: w2[g*4+j][qd*4 .. qd*4+3][0..8]
                const float4* w4 = reinterpret_cast<const float4*>(wbv + j * 144 + qd * 36);
                float4 wq[9];
#pragma unroll
                for (int t = 0; t < 9; ++t) wq[t] = w4[t];

#pragma unroll
                for (int c4 = 0; c4 < 4; ++c4) {
#pragma unroll
                    for (int kh = 0; kh < 9; ++kh) {
                        const int wi = c4 * 9 + kh;
                        float wv  = F4C(wq[wi >> 2], wi & 3);
                        float xlo = (kh & 1) ? F4C(wo[kh >> 1], c4)
                                             : F4C(we[kh >> 1], c4);        // tap kh
                        float xhi = (kh & 1) ? F4C(we[(kh + 1) >> 1], c4)
                                             : F4C(wo[kh >> 1], c4);        // tap kh+1
                        a0[j] += wv * xlo;     // h = 2p
                        a1[j] += wv * xhi;     // h = 2p+1
                    }
                }
            }
        }
        float r3t[4];
#pragma unroll
        for (int j = 0; j < 4; ++j) {
            float r20 = spike_rate(a0[j], ratetbl);
            float r21 = spike_rate(a1[j], ratetbl);
            r3t[j] = spike_rate_nb(1.1f * (r20 + r21), ratetbl);
        }
        if (act) r3q[g][p + 1] = make_float4(r3t[0], r3t[1], r3t[2], r3t[3]);
    }
    __syncthreads();

    // ---- phase 4: conv3 (32->32, k=7, pad=1) + rate ----
    // 16 waves = 8 out-ch-groups(4) x 2 h-halves; lanes -> h.
    // Taps: 7 ds_read_b128 per quad, 1-deep prefetch (now survives: weight
    // waits are vmcnt). Weights: per (j,q) 7 aligned float4 VMEM loads.
    {
        const int gg   = __builtin_amdgcn_readfirstlane(wave >> 1);  // 0..7
        const int g4   = gg * 4;
        const int half = wave & 1;
        const int cnt  = half ? 41 : 42;
        const bool act = lane < cnt;
        const int h0   = half * 42 + lane;    // valid max 82; window max 88
        const int hr   = act ? h0 : 0;
        const float* wbv = w3 + g4 * 224 + vzero;   // VGPR-dependent base

        float a[4];
#pragma unroll
        for (int j = 0; j < 4; ++j) a[j] = b3[g4 + j];

        float4 rv[7];
#pragma unroll
        for (int d = 0; d < 7; ++d) rv[d] = r3q[0][hr + d];

#pragma unroll 1
        for (int q = 0; q < 8; ++q) {
            const int qn = (q < 7) ? q + 1 : 7;
            float4 rn[7];
#pragma unroll
            for (int d = 0; d < 7; ++d) rn[d] = r3q[qn][hr + d];

#pragma unroll
            for (int j = 0; j < 4; ++j) {
                // 28 contiguous floats: w3[g4+j][q*4 .. q*4+3][0..6]
                const float4* w4 = reinterpret_cast<const float4*>(wbv + j * 224 + q * 28);
                float4 wq[7];
#pragma unroll
                for (int t = 0; t < 7; ++t) wq[t] = w4[t];

#pragma unroll
                for (int c4 = 0; c4 < 4; ++c4) {
#pragma unroll
                    for (int kh = 0; kh < 7; ++kh) {
                        const int wi = c4 * 7 + kh;
                        a[j] += F4C(wq[wi >> 2], wi & 3) * F4C(rv[kh], c4);
                    }
                }
            }
#pragma unroll
            for (int d = 0; d < 7; ++d) rv[d] = rn[d];
        }
#pragma unroll
        for (int j = 0; j < 4; ++j) {
            float r = spike_rate(a[j], ratetbl);
            if (act) r4s[g4 + j][h0] = r;
        }
    }
    __syncthreads();

    // ---- phase 5: dense [32*83] -> 4 outputs; 4 waves per output, float2 ----
    {
        const int o = wave >> 2, q = wave & 3;
        const float2* r42 = reinterpret_cast<const float2*>(&r4s[0][0]);
        const float2* wo2 = reinterpret_cast<const float2*>(wf + o * (32 * 83));
        float acc = 0.f;
        for (int j = q * 64 + lane; j < 1328; j += 256) {
            float2 rv = r42[j], wv = wo2[j];
            acc += rv.x * wv.x + rv.y * wv.y;
        }
#pragma unroll
        for (int off = 32; off > 0; off >>= 1)
            acc += __shfl_down(acc, off, 64);
        if (lane == 0) part[wave] = acc;
    }
    __syncthreads();
    if (tid < 4) {
        float s = part[tid*4] + part[tid*4+1] + part[tid*4+2] + part[tid*4+3];
        out[n * 4 + tid] = s + bf[tid];
    }
}

extern "C" void kernel_launch(void* const* d_in, const int* in_sizes, int n_in,
                              void* d_out, int out_size, void* d_ws, size_t ws_size,
                              hipStream_t stream) {
    const float* x  = (const float*)d_in[0];
    const float* w1 = (const float*)d_in[1];
    const float* b1 = (const float*)d_in[2];
    const float* w2 = (const float*)d_in[3];
    const float* b2 = (const float*)d_in[4];
    const float* w3 = (const float*)d_in[5];
    const float* b3 = (const float*)d_in[6];
    const float* wf = (const float*)d_in[7];
    const float* bf = (const float*)d_in[8];
    float* outp = (float*)d_out;

    catnet_kernel<<<dim3(256), dim3(1024), 0, stream>>>(
        x, w1, b1, w2, b2, w3, b3, wf, bf, outp);
}

// Round 10
// 109.971 us; speedup vs baseline: 1.2439x; 1.2439x over previous
//
#include <hip/hip_runtime.h>

// CatNet_76553497084407 — SLAYER-style spiking CNN, fully collapsed over time.
//
// R17 = R13 internals (ci-quad float4 DS layout, s_load weights, best 99.2us)
// quartered into 4 blocks/CU to reach 8 waves/SIMD.
//
// Why: at R13 static accounting gives VALU ~20k cyc/SIMD, DS ~19k cyc/CU vs
// an 84k-cycle wall — both pipes ~23% busy; no within-wave stall model closes
// the gap, and all within-wave fixes were null. The one untested axis is
// waves/SIMD: R11 split domains at CONSTANT 16 waves/CU (null); R12 hit 32
// waves (occ 73%) but was confounded by per-lane weight addresses (vector
// loads, +170%). R17 runs the R12 geometry unconfounded:
//   * grid 1024 = 256 images x 4 quarters, 512 thr; R12's validated ranges.
//   * weights wave-uniform s_load (wave = oc-group of 4; NO per-lane jj).
//   * inactive lanes EXEC-masked (if(act)) -> no duplicate DS traffic;
//     active lanes sit in the lower half (p_cnt<=28, h_cnt<=21).
//   * bounds(512,8) caps VGPR at 64 (R13 used 44; phase-4 tap prefetch
//     dropped - measured null in R15).
//   * partials via __device__ g_part + finish kernel (R11/R12 pattern).
// Discriminator: latency-bound -> ~22-30us kernel; slot-bound (halo +25%)
// -> ~45-55us, then revert to R13 and declare plateau.
// Spill tripwire: WRITE_SIZE must stay ~tens of KB.

#define T_STEPS 50
#define THETA   0.9999f

__device__ float g_part[256 * 16];   // [n][quarter][o] partial dense sums

// component of a float4 by compile-time index (folds after unroll)
#define F4C(v, c) ((c) == 0 ? (v).x : (c) == 1 ? (v).y : (c) == 2 ? (v).z : (v).w)

// Exact-rounding rate: tbl[c] == c/50.0f computed with a true divide once.
__device__ __forceinline__ float spike_rate(float a, const float* __restrict__ tbl) {
    constexpr float INV = 50.0f / 0.9999f;
    float t = a * INV;
    float c = fminf(fmaxf(floorf(t), 0.0f), 50.0f);
    // fall back to the exact 50-step f32 sim when t is near an integer
    bool risky = (t > 0.5f) && (fabsf(t - rintf(t)) < 2e-4f);
    if (__ballot(risky)) {
        float v = 0.f, cnt = 0.f;
#pragma unroll 1
        for (int k = 0; k < T_STEPS; ++k) {
            v += a;
            float s = (v >= THETA) ? 1.0f : 0.0f;
            v -= s * THETA;
            cnt += s;
        }
        c = cnt;
    }
    return tbl[(int)c];
}

// No-ballot variant: only legal when the input provably cannot sit within
// 2e-4 of an integer boundary in t-units (pooled path: 1.1*k/50, margin 1.1e-3).
__device__ __forceinline__ float spike_rate_nb(float a, const float* __restrict__ tbl) {
    constexpr float INV = 50.0f / 0.9999f;
    float t = a * INV;
    float c = fminf(fmaxf(floorf(t), 0.0f), 50.0f);
    return tbl[(int)c];
}

extern "C" __global__ void __launch_bounds__(512, 8)
catnet_split(const float* __restrict__ x,
             const float* __restrict__ w1, const float* __restrict__ b1,
             const float* __restrict__ w2, const float* __restrict__ b2,
             const float* __restrict__ w3, const float* __restrict__ b3,
             const float* __restrict__ wf)
{
    const int n    = blockIdx.x >> 2;
    const int qt   = blockIdx.x & 3;
    const int tid  = threadIdx.x;
    const int wave = tid >> 6;
    const int lane = tid & 63;

    // Quarter ranges (validated in R12): conv-chain back-propagated halos.
    const int h_lo_t[4]  = {0, 21, 42, 63},  h_cnt_t[4]  = {21, 21, 21, 20};
    const int p_lo_t[4]  = {0, 20, 41, 62},  p_cnt_t[4]  = {27, 28, 28, 25};
    const int r1_lo_t[4] = {0, 39, 81, 123}, r1_cnt_t[4] = {62, 65, 65, 57};
    const int x_lo_t[4]  = {0, 38, 80, 122}, x_cnt_t[4]  = {63, 67, 67, 58};
    const int h_lo  = h_lo_t[qt],  h_cnt  = h_cnt_t[qt];
    const int p_lo  = p_lo_t[qt],  p_cnt  = p_cnt_t[qt];
    const int r1_lo = r1_lo_t[qt], r1_cnt = r1_cnt_t[qt];
    const int x_lo  = x_lo_t[qt],  x_cnt  = x_cnt_t[qt];

    __shared__ float  xbar[182];        // [h+1], global padded idx
    __shared__ float4 r1qe[4][92];      // [ciq][i] = conv1 rate, even padded H=2i
    __shared__ float4 r1qo[4][92];      // [ciq][i] = odd padded H=2i+1
    __shared__ float4 r3q[8][89];       // [ciq][p+1] = pooled rate, ci quad
    __shared__ alignas(16) float r4s[32][83];
    __shared__ float  ratetbl[51];      // exact c/50.0f
    __shared__ float  part[8];

    // zero conv pads + build exact-rate table (pads harmless if unused by qt)
    const float4 z4 = make_float4(0.f, 0.f, 0.f, 0.f);
    if (tid < 4)               r1qe[tid][0]       = z4;   // H=0 pad
    if (tid >= 4  && tid < 8)  r1qo[tid - 4][90]  = z4;   // H=181 pad
    if (tid >= 8  && tid < 16) r3q[tid - 8][0]    = z4;   // p_idx=0 pad
    if (tid >= 16 && tid < 24) r3q[tid - 16][88]  = z4;   // p_idx=88 pad
    if (tid == 64)             { xbar[0] = 0.f; xbar[181] = 0.f; }
    if (tid >= 128 && tid < 179) ratetbl[tid - 128] = (float)(tid - 128) / 50.0f;

    // ---- phase 0: time-sum of this quarter's x rows, 4 lanes per row ----
    const float* xn = x + (size_t)n * (180 * 50);
    if (tid < 4 * x_cnt) {
        const int h_l = tid >> 2, q = tid & 3;
        const int h   = x_lo + h_l;
        const float2* row2 = reinterpret_cast<const float2*>(xn + h * 50);
        float s = 0.f;
        for (int k = q; k < 24; k += 4) { float2 v = row2[k]; s += v.x + v.y; }
        if (q == 0)                     { float2 v = row2[24]; s += v.x + v.y; }
        s += __shfl_xor(s, 1, 4);
        s += __shfl_xor(s, 2, 4);
        if (q == 0) xbar[h + 1] = s;
    }
    __syncthreads();

    // ---- phase 1: conv1 (1->16, k=3, pad=1), /T, +b1, rate; quarter rows ----
    for (int idx = tid; idx < 16 * 128; idx += 512) {
        const int c = idx >> 7, h_l = idx & 127;
        const bool act = h_l < r1_cnt;
        const int h = r1_lo + (act ? h_l : 0);
        float a = w1[c*3+0] * xbar[h] + w1[c*3+1] * xbar[h+1] + w1[c*3+2] * xbar[h+2];
        a = a / 50.0f + b1[c];
        float r = spike_rate(a, ratetbl);
        if (act) {
            int H = h + 1;
            float* dst = (H & 1) ? (float*)&r1qo[c >> 2][H >> 1]
                                 : (float*)&r1qe[c >> 2][H >> 1];
            dst[c & 3] = r;
        }
    }
    __syncthreads();

    // ---- phase 2: conv2 (16->32, k=9, pad=1) + rate + pool(2)*1.1 + rate ----
    // 8 waves, wave = out-ch group g (4 oc, wave-uniform -> s_load weights).
    // Lane = pool col within quarter (p_cnt <= 28, lower half of the wave);
    // inactive lanes EXEC-masked off -> no DS traffic.
    {
        const int g   = __builtin_amdgcn_readfirstlane(wave);   // 0..7
        if (lane < p_cnt) {
            const int p = p_lo + lane;
            const float* wb = w2 + g * 4 * 144;   // [oc][ci][kh], oc stride 144

            float a0[4], a1[4];
#pragma unroll
            for (int j = 0; j < 4; ++j) { a0[j] = b2[g*4 + j]; a1[j] = a0[j]; }

#pragma unroll 1
            for (int qd = 0; qd < 4; ++qd) {
                float4 we[5], wo[5];
#pragma unroll
                for (int d = 0; d < 5; ++d) { we[d] = r1qe[qd][p + d]; wo[d] = r1qo[qd][p + d]; }

#pragma unroll
                for (int c4 = 0; c4 < 4; ++c4) {
                    const int ci = qd * 4 + c4;
#pragma unroll
                    for (int j = 0; j < 4; ++j) {
                        const float* wj = wb + j * 144 + ci * 9;
#pragma unroll
                        for (int kh = 0; kh < 9; ++kh) {
                            float wv  = wj[kh];
                            float xlo = (kh & 1) ? F4C(wo[kh >> 1], c4)
                                                 : F4C(we[kh >> 1], c4);        // tap kh
                            float xhi = (kh & 1) ? F4C(we[(kh + 1) >> 1], c4)
                                                 : F4C(wo[kh >> 1], c4);        // tap kh+1
                            a0[j] += wv * xlo;     // h = 2p
                            a1[j] += wv * xhi;     // h = 2p+1
                        }
                    }
                }
            }
            float r3t[4];
#pragma unroll
            for (int j = 0; j < 4; ++j) {
                float r20 = spike_rate(a0[j], ratetbl);
                float r21 = spike_rate(a1[j], ratetbl);
                r3t[j] = spike_rate_nb(1.1f * (r20 + r21), ratetbl);
            }
            r3q[g][p + 1] = make_float4(r3t[0], r3t[1], r3t[2], r3t[3]);
        }
    }
    __syncthreads();

    // ---- phase 4: conv3 (32->32, k=7, pad=1) + rate; quarter h rows ----
    // 8 waves, wave = out-ch group (4 oc); lanes over quarter h (h_cnt <= 21).
    {
        const int gg = __builtin_amdgcn_readfirstlane(wave);   // 0..7
        const int g4 = gg * 4;
        if (lane < h_cnt) {
            const int h0 = h_lo + lane;
            const float* wb = w3 + g4 * 224;      // [oc][ci][kh], oc stride 224

            float a[4];
#pragma unroll
            for (int j = 0; j < 4; ++j) a[j] = b3[g4 + j];

#pragma unroll 1
            for (int q = 0; q < 8; ++q) {
                float4 rv[7];
#pragma unroll
                for (int d = 0; d < 7; ++d) rv[d] = r3q[q][h0 + d];

#pragma unroll
                for (int c4 = 0; c4 < 4; ++c4) {
                    const int ci = q * 4 + c4;
#pragma unroll
                    for (int j = 0; j < 4; ++j) {
                        const float* wj = wb + j * 224 + ci * 7;
#pragma unroll
                        for (int kh = 0; kh < 7; ++kh)
                            a[j] += wj[kh] * F4C(rv[kh], c4);
                    }
                }
            }
#pragma unroll
            for (int j = 0; j < 4; ++j)
                r4s[g4 + j][h0] = spike_rate(a[j], ratetbl);
        }
    }
    __syncthreads();

    // ---- phase 5: partial dense over quarter h rows; 2 waves per output ----
    {
        const int o = wave >> 1, q = wave & 1;
        float acc = 0.f;
        if (lane < h_cnt) {
            const int h0 = h_lo + lane;
            const float* wo = wf + o * (32 * 83);
            for (int c = q; c < 32; c += 2)
                acc += r4s[c][h0] * wo[c * 83 + h0];
        }
#pragma unroll
        for (int off = 32; off > 0; off >>= 1)
            acc += __shfl_down(acc, off, 64);
        if (lane == 0) part[wave] = acc;
    }
    __syncthreads();
    if (tid < 4)
        g_part[n * 16 + qt * 4 + tid] = part[2 * tid] + part[2 * tid + 1];
}

extern "C" __global__ void __launch_bounds__(256)
catnet_finish(const float* __restrict__ bf, float* __restrict__ out)
{
    const int i = blockIdx.x * 256 + threadIdx.x;   // 1024 = 256 n x 4 o
    if (i < 1024) {
        const int n = i >> 2, o = i & 3;
        out[i] = g_part[n * 16 + o]     + g_part[n * 16 + 4 + o]
               + g_part[n * 16 + 8 + o] + g_part[n * 16 + 12 + o] + bf[o];
    }
}

extern "C" void kernel_launch(void* const* d_in, const int* in_sizes, int n_in,
                              void* d_out, int out_size, void* d_ws, size_t ws_size,
                              hipStream_t stream) {
    const float* x  = (const float*)d_in[0];
    const float* w1 = (const float*)d_in[1];
    const float* b1 = (const float*)d_in[2];
    const float* w2 = (const float*)d_in[3];
    const float* b2 = (const float*)d_in[4];
    const float* w3 = (const float*)d_in[5];
    const float* b3 = (const float*)d_in[6];
    const float* wf = (const float*)d_in[7];
    const float* bf = (const float*)d_in[8];
    float* outp = (float*)d_out;

    catnet_split<<<dim3(1024), dim3(512), 0, stream>>>(
        x, w1, b1, w2, b2, w3, b3, wf);
    catnet_finish<<<dim3(4), dim3(256), 0, stream>>>(bf, outp);
}

// Round 13
// 98.511 us; speedup vs baseline: 1.3886x; 1.1163x over previous
//
#include <hip/hip_runtime.h>

// CatNet_76553497084407 — SLAYER-style spiking CNN, fully collapsed over time.
//
// R20 = R13 restored (best: 99.2us bench, kernel ~35us, absmax 0.0) + the
// last zero-risk slot cut: phase-5 dense reads as float4 (664 b128/dwordx4
// vs 1328 b64/dwordx2; r4s is alignas(16), wf row offsets o*2656*4B are
// 16B-aligned). No other changes.
//
// R18/R19 packed-fp32 attempt is ABANDONED: two consecutive container
// failures, the second after removing __builtin_elementwise_fma — the common
// construct is ext_vector f32 ARITHMETIC (vector loads/extracts are used
// throughout this kernel and run fine; vector fmul/fma ISel is the new path).
// Deterministic toolchain kill, not infra. The op_sel inline-asm workaround
// nets ~2% after the SGPR->VGPR-pair mov tax; not worth the risk.
//
// Final model (12 rounds of evidence): the kernel is wave-ISSUE-SLOT bound.
//   time ~ slots: R9 +DS -> +16%; R12 +VMEM -> +170%; R13 -75% DS -> -15%;
//   R17 +25% work (at 2x occupancy!) -> +23%.
//   null: R8 (-conflicts, -divide), R11 (+barrier domains), R15 (prefetch).
//   negative: R14 (slot cut that idled waves), R16 (weights SMEM->VMEM).
// Measured VALU ~45% busy (dominant), DS ~23%; remaining levers <= ~2%.
//
// Kernel structure: ci-quad float4 interstage layouts (one ds_read_b128 =
// one window tap x 4 input channels), wave-uniform s_load weights, 16-wave
// mapping, exact c/50 LDS rate table, 2e-4 risky threshold with 50-step sim
// fallback, no-ballot pooled rate, single dispatch.
// Spill tripwire: WRITE_SIZE must stay ~tens of KB (spills were 190MB+).

#define T_STEPS 50
#define THETA   0.9999f

// component of a float4 by compile-time index (folds after unroll)
#define F4C(v, c) ((c) == 0 ? (v).x : (c) == 1 ? (v).y : (c) == 2 ? (v).z : (v).w)

// Exact-rounding rate: tbl[c] == c/50.0f computed with a true divide once.
__device__ __forceinline__ float spike_rate(float a, const float* __restrict__ tbl) {
    constexpr float INV = 50.0f / 0.9999f;
    float t = a * INV;
    float c = fminf(fmaxf(floorf(t), 0.0f), 50.0f);
    // fall back to the exact 50-step f32 sim when t is near an integer
    bool risky = (t > 0.5f) && (fabsf(t - rintf(t)) < 2e-4f);
    if (__ballot(risky)) {
        float v = 0.f, cnt = 0.f;
#pragma unroll 1
        for (int k = 0; k < T_STEPS; ++k) {
            v += a;
            float s = (v >= THETA) ? 1.0f : 0.0f;
            v -= s * THETA;
            cnt += s;
        }
        c = cnt;
    }
    return tbl[(int)c];
}

// No-ballot variant: only legal when the input provably cannot sit within
// 2e-4 of an integer boundary in t-units (pooled path: 1.1*k/50, margin 1.1e-3).
__device__ __forceinline__ float spike_rate_nb(float a, const float* __restrict__ tbl) {
    constexpr float INV = 50.0f / 0.9999f;
    float t = a * INV;
    float c = fminf(fmaxf(floorf(t), 0.0f), 50.0f);
    return tbl[(int)c];
}

extern "C" __global__ void __launch_bounds__(1024, 4)
catnet_kernel(const float* __restrict__ x,
              const float* __restrict__ w1, const float* __restrict__ b1,
              const float* __restrict__ w2, const float* __restrict__ b2,
              const float* __restrict__ w3, const float* __restrict__ b3,
              const float* __restrict__ wf, const float* __restrict__ bf,
              float* __restrict__ out)
{
    const int n    = blockIdx.x;
    const int tid  = threadIdx.x;
    const int wave = tid >> 6;
    const int lane = tid & 63;

    __shared__ float  xbar[182];        // [h+1], h in [0,180)
    __shared__ float4 r1qe[4][92];      // [ciq][i] = conv1 rate at even padded H=2i, ci quad
    __shared__ float4 r1qo[4][92];      // [ciq][i] = odd padded H=2i+1
    __shared__ float4 r3q[8][89];       // [ciq][p+1] = pooled rate, ci quad
    __shared__ alignas(16) float r4s[32][83];
    __shared__ float  ratetbl[51];      // exact c/50.0f
    __shared__ float  part[16];

    // zero conv pads + build exact-rate table
    const float4 z4 = make_float4(0.f, 0.f, 0.f, 0.f);
    if (tid < 4)               r1qe[tid][0]       = z4;   // H=0 pad
    if (tid >= 4  && tid < 8)  r1qo[tid - 4][90]  = z4;   // H=181 pad
    if (tid >= 8  && tid < 16) r3q[tid - 8][0]    = z4;   // p_idx=0 pad
    if (tid >= 16 && tid < 24) r3q[tid - 16][88]  = z4;   // p_idx=88 pad
    if (tid == 64)             { xbar[0] = 0.f; xbar[181] = 0.f; }
    if (tid >= 128 && tid < 179) ratetbl[tid - 128] = (float)(tid - 128) / 50.0f;

    // ---- phase 0: time-sum of input, 4 lanes per h, float2 loads ----
    const float* xn = x + (size_t)n * (180 * 50);
    if (tid < 720) {
        const int h = tid >> 2, q = tid & 3;
        const float2* row2 = reinterpret_cast<const float2*>(xn + h * 50);
        float s = 0.f;
        for (int k = q; k < 24; k += 4) { float2 v = row2[k]; s += v.x + v.y; }
        if (q == 0)                     { float2 v = row2[24]; s += v.x + v.y; }
        s += __shfl_xor(s, 1, 4);
        s += __shfl_xor(s, 2, 4);
        if (q == 0) xbar[h + 1] = s;
    }
    __syncthreads();

    // ---- phase 1: conv1 (1->16, k=3, pad=1), /T, +b1, rate ----
    for (int idx = tid; idx < 16 * 180; idx += 1024) {
        int c = idx / 180, h = idx - c * 180;
        float a = w1[c*3+0] * xbar[h] + w1[c*3+1] * xbar[h+1] + w1[c*3+2] * xbar[h+2];
        a = a / 50.0f + b1[c];
        float r = spike_rate(a, ratetbl);
        int H = h + 1;
        float* dst = (H & 1) ? (float*)&r1qo[c >> 2][H >> 1]
                             : (float*)&r1qe[c >> 2][H >> 1];
        dst[c & 3] = r;
    }
    __syncthreads();

    // ---- phase 2: conv2 (16->32, k=9, pad=1) + rate + pool(2)*1.1 + rate ----
    // 8 groups of 128 threads: g = tid>>7 (wave-uniform), p = tid&127 < 87.
    // Thread computes conv2 at h=2p,2p+1 (shared 10-tap window) for 4 out-ch.
    // Per ci-quad: 10 ds_read_b128 = window taps for 4 input channels.
    // Tap d (padded H=2p+d): d even -> F4C(we[d/2]), d odd -> F4C(wo[(d-1)/2]).
    {
        const int g   = __builtin_amdgcn_readfirstlane(tid >> 7);   // 0..7
        const int p   = tid & 127;
        const bool act = p < 87;
        const int pr  = act ? p : 0;
        const float* wb = w2 + g * 4 * 144;   // [oc][ci][kh], oc stride 144

        float a0[4], a1[4];
#pragma unroll
        for (int j = 0; j < 4; ++j) { a0[j] = b2[g*4 + j]; a1[j] = a0[j]; }

#pragma unroll 1
        for (int qd = 0; qd < 4; ++qd) {
            float4 we[5], wo[5];
#pragma unroll
            for (int d = 0; d < 5; ++d) { we[d] = r1qe[qd][pr + d]; wo[d] = r1qo[qd][pr + d]; }

#pragma unroll
            for (int c4 = 0; c4 < 4; ++c4) {
                const int ci = qd * 4 + c4;
#pragma unroll
                for (int j = 0; j < 4; ++j) {
                    const float* wj = wb + j * 144 + ci * 9;
#pragma unroll
                    for (int kh = 0; kh < 9; ++kh) {
                        float wv  = wj[kh];
                        float xlo = (kh & 1) ? F4C(wo[kh >> 1], c4)
                                             : F4C(we[kh >> 1], c4);        // tap kh
                        float xhi = (kh & 1) ? F4C(we[(kh + 1) >> 1], c4)
                                             : F4C(wo[kh >> 1], c4);        // tap kh+1
                        a0[j] += wv * xlo;     // h = 2p
                        a1[j] += wv * xhi;     // h = 2p+1
                    }
                }
            }
        }
        float r3t[4];
#pragma unroll
        for (int j = 0; j < 4; ++j) {
            float r20 = spike_rate(a0[j], ratetbl);
            float r21 = spike_rate(a1[j], ratetbl);
            r3t[j] = spike_rate_nb(1.1f * (r20 + r21), ratetbl);
        }
        if (act) r3q[g][p + 1] = make_float4(r3t[0], r3t[1], r3t[2], r3t[3]);
    }
    __syncthreads();

    // ---- phase 4: conv3 (32->32, k=7, pad=1) + rate ----
    // 16 waves = 8 out-ch-groups(4) x 2 h-halves; lanes -> h.
    // Per ci-quad: 7 ds_read_b128 window taps (4 input channels each).
    {
        const int gg   = __builtin_amdgcn_readfirstlane(wave >> 1);  // 0..7
        const int g4   = gg * 4;
        const int half = wave & 1;
        const int cnt  = half ? 41 : 42;
        const bool act = lane < cnt;
        const int h0   = half * 42 + lane;    // valid max 82; window max 88
        const int hr   = act ? h0 : 0;
        const float* wb = w3 + g4 * 224;      // [oc][ci][kh], oc stride 224

        float a[4];
#pragma unroll
        for (int j = 0; j < 4; ++j) a[j] = b3[g4 + j];

#pragma unroll 1
        for (int q = 0; q < 8; ++q) {
            float4 rv[7];
#pragma unroll
            for (int d = 0; d < 7; ++d) rv[d] = r3q[q][hr + d];

#pragma unroll
            for (int c4 = 0; c4 < 4; ++c4) {
                const int ci = q * 4 + c4;
#pragma unroll
                for (int j = 0; j < 4; ++j) {
                    const float* wj = wb + j * 224 + ci * 7;
#pragma unroll
                    for (int kh = 0; kh < 7; ++kh)
                        a[j] += wj[kh] * F4C(rv[kh], c4);
                }
            }
        }
#pragma unroll
        for (int j = 0; j < 4; ++j) {
            float r = spike_rate(a[j], ratetbl);
            if (act) r4s[g4 + j][h0] = r;
        }
    }
    __syncthreads();

    // ---- phase 5: dense [32*83] -> 4 outputs; 4 waves per output, float4 ----
    // 664 float4s cover the 2656-elem tensor exactly; r4s alignas(16), wf row
    // offset o*2656*4B is 16B-aligned. Pairwise adds inside each float4 keep
    // the summation tree shallow.
    {
        const int o = wave >> 2, q = wave & 3;
        const float4* r44 = reinterpret_cast<const float4*>(&r4s[0][0]);
        const float4* wo4 = reinterpret_cast<const float4*>(wf + o * (32 * 83));
        float acc = 0.f;
        for (int j = q * 64 + lane; j < 664; j += 256) {
            float4 rv = r44[j], wv = wo4[j];
            acc += rv.x * wv.x + rv.y * wv.y;
            acc += rv.z * wv.z + rv.w * wv.w;
        }
#pragma unroll
        for (int off = 32; off > 0; off >>= 1)
            acc += __shfl_down(acc, off, 64);
        if (lane == 0) part[wave] = acc;
    }
    __syncthreads();
    if (tid < 4) {
        float s = part[tid*4] + part[tid*4+1] + part[tid*4+2] + part[tid*4+3];
        out[n * 4 + tid] = s + bf[tid];
    }
}

extern "C" void kernel_launch(void* const* d_in, const int* in_sizes, int n_in,
                              void* d_out, int out_size, void* d_ws, size_t ws_size,
                              hipStream_t stream) {
    const float* x  = (const float*)d_in[0];
    const float* w1 = (const float*)d_in[1];
    const float* b1 = (const float*)d_in[2];
    const float* w2 = (const float*)d_in[3];
    const float* b2 = (const float*)d_in[4];
    const float* w3 = (const float*)d_in[5];
    const float* b3 = (const float*)d_in[6];
    const float* wf = (const float*)d_in[7];
    const float* bf = (const float*)d_in[8];
    float* outp = (float*)d_out;

    catnet_kernel<<<dim3(256), dim3(1024), 0, stream>>>(
        x, w1, b1, w2, b2, w3, b3, wf, bf, outp);
}

// Round 14
// 97.123 us; speedup vs baseline: 1.4084x; 1.0143x over previous
//
#include <hip/hip_runtime.h>

// CatNet_76553497084407 — SLAYER-style spiking CNN, fully collapsed over time.
//
// R21 = R20 (best: 98.5us bench, absmax 0.0) + phase-1 wave=channel remap.
// Old phase 1: idx/180 made c lane-varying -> integer div (~4 VALU x 3 iter)
// AND per-lane vector loads for w1/b1 (~10 VMEM slots/thread). New: wave =
// channel (16 waves = 16 channels), c wave-uniform -> w1/b1 s_load (free),
// no div; lanes sweep h in 3 strips of 64 (180 = 64+64+52). Per-output FMA
// expression, /50.0f true-divide rounding, spike_rate semantics unchanged;
// ballot regrouping benign (non-risky lanes' sim count == fast count by the
// 2e-4 margin) -> absmax 0.0 preserved.
//
// Final model (14 rounds): the kernel is wave-ISSUE-SLOT bound.
//   time ~ slots: R9 +DS -> +16%; R12 +VMEM -> +170%; R13 -75% DS -> -15%;
//   R17 +25% work (at 2x occupancy!) -> +23%; R20 small cut -> small win.
//   null: R8 (-conflicts, -divide), R11 (+barrier domains), R15 (prefetch).
//   negative: R14 (slot cut that idled waves), R16 (weights SMEM->VMEM).
//   blocked: packed fp32 (R18/R19 deterministic toolchain kill on ext_vector
//   f32 arithmetic; op_sel asm variant unverifiable + pair-build mov tax).
// If this round lands <=1us with no new counter signal, next round declares
// the plateau: wall ~82k cyc vs ~37k overlapped slot floor, all structural
// levers measured null/negative, remaining ideas <=2% or crash-risky.
//
// Kernel structure: ci-quad float4 interstage layouts (one ds_read_b128 =
// one window tap x 4 input channels), wave-uniform s_load weights, 16-wave
// mapping, exact c/50 LDS rate table, 2e-4 risky threshold with 50-step sim
// fallback, no-ballot pooled rate, float4 dense, single dispatch.
// Spill tripwire: WRITE_SIZE must stay ~tens of KB (spills were 190MB+).

#define T_STEPS 50
#define THETA   0.9999f

// component of a float4 by compile-time index (folds after unroll)
#define F4C(v, c) ((c) == 0 ? (v).x : (c) == 1 ? (v).y : (c) == 2 ? (v).z : (v).w)

// Exact-rounding rate: tbl[c] == c/50.0f computed with a true divide once.
__device__ __forceinline__ float spike_rate(float a, const float* __restrict__ tbl) {
    constexpr float INV = 50.0f / 0.9999f;
    float t = a * INV;
    float c = fminf(fmaxf(floorf(t), 0.0f), 50.0f);
    // fall back to the exact 50-step f32 sim when t is near an integer
    bool risky = (t > 0.5f) && (fabsf(t - rintf(t)) < 2e-4f);
    if (__ballot(risky)) {
        float v = 0.f, cnt = 0.f;
#pragma unroll 1
        for (int k = 0; k < T_STEPS; ++k) {
            v += a;
            float s = (v >= THETA) ? 1.0f : 0.0f;
            v -= s * THETA;
            cnt += s;
        }
        c = cnt;
    }
    return tbl[(int)c];
}

// No-ballot variant: only legal when the input provably cannot sit within
// 2e-4 of an integer boundary in t-units (pooled path: 1.1*k/50, margin 1.1e-3).
__device__ __forceinline__ float spike_rate_nb(float a, const float* __restrict__ tbl) {
    constexpr float INV = 50.0f / 0.9999f;
    float t = a * INV;
    float c = fminf(fmaxf(floorf(t), 0.0f), 50.0f);
    return tbl[(int)c];
}

extern "C" __global__ void __launch_bounds__(1024, 4)
catnet_kernel(const float* __restrict__ x,
              const float* __restrict__ w1, const float* __restrict__ b1,
              const float* __restrict__ w2, const float* __restrict__ b2,
              const float* __restrict__ w3, const float* __restrict__ b3,
              const float* __restrict__ wf, const float* __restrict__ bf,
              float* __restrict__ out)
{
    const int n    = blockIdx.x;
    const int tid  = threadIdx.x;
    const int wave = tid >> 6;
    const int lane = tid & 63;

    __shared__ float  xbar[182];        // [h+1], h in [0,180)
    __shared__ float4 r1qe[4][92];      // [ciq][i] = conv1 rate at even padded H=2i, ci quad
    __shared__ float4 r1qo[4][92];      // [ciq][i] = odd padded H=2i+1
    __shared__ float4 r3q[8][89];       // [ciq][p+1] = pooled rate, ci quad
    __shared__ alignas(16) float r4s[32][83];
    __shared__ float  ratetbl[51];      // exact c/50.0f
    __shared__ float  part[16];

    // zero conv pads + build exact-rate table
    const float4 z4 = make_float4(0.f, 0.f, 0.f, 0.f);
    if (tid < 4)               r1qe[tid][0]       = z4;   // H=0 pad
    if (tid >= 4  && tid < 8)  r1qo[tid - 4][90]  = z4;   // H=181 pad
    if (tid >= 8  && tid < 16) r3q[tid - 8][0]    = z4;   // p_idx=0 pad
    if (tid >= 16 && tid < 24) r3q[tid - 16][88]  = z4;   // p_idx=88 pad
    if (tid == 64)             { xbar[0] = 0.f; xbar[181] = 0.f; }
    if (tid >= 128 && tid < 179) ratetbl[tid - 128] = (float)(tid - 128) / 50.0f;

    // ---- phase 0: time-sum of input, 4 lanes per h, float2 loads ----
    const float* xn = x + (size_t)n * (180 * 50);
    if (tid < 720) {
        const int h = tid >> 2, q = tid & 3;
        const float2* row2 = reinterpret_cast<const float2*>(xn + h * 50);
        float s = 0.f;
        for (int k = q; k < 24; k += 4) { float2 v = row2[k]; s += v.x + v.y; }
        if (q == 0)                     { float2 v = row2[24]; s += v.x + v.y; }
        s += __shfl_xor(s, 1, 4);
        s += __shfl_xor(s, 2, 4);
        if (q == 0) xbar[h + 1] = s;
    }
    __syncthreads();

    // ---- phase 1: conv1 (1->16, k=3, pad=1), /T, +b1, rate ----
    // wave = channel (wave-uniform -> s_load w1/b1, no int div); lanes sweep
    // h in 3 strips of 64 (180 = 64+64+52). Same per-output FMA expression
    // and /50.0f rounding as before -> bit-identical r1.
    {
        const int c  = __builtin_amdgcn_readfirstlane(wave);   // 0..15
        const float wA = w1[c*3+0], wB = w1[c*3+1], wC = w1[c*3+2];
        const float bb = b1[c];
#pragma unroll
        for (int i = 0; i < 3; ++i) {
            const int h = i * 64 + lane;
            const bool act = h < 180;
            const int hh = act ? h : 0;
            float a = wA * xbar[hh] + wB * xbar[hh+1] + wC * xbar[hh+2];
            a = a / 50.0f + bb;
            float r = spike_rate(a, ratetbl);
            if (act) {
                int H = hh + 1;
                float* dst = (H & 1) ? (float*)&r1qo[c >> 2][H >> 1]
                                     : (float*)&r1qe[c >> 2][H >> 1];
                dst[c & 3] = r;
            }
        }
    }
    __syncthreads();

    // ---- phase 2: conv2 (16->32, k=9, pad=1) + rate + pool(2)*1.1 + rate ----
    // 8 groups of 128 threads: g = tid>>7 (wave-uniform), p = tid&127 < 87.
    // Thread computes conv2 at h=2p,2p+1 (shared 10-tap window) for 4 out-ch.
    // Per ci-quad: 10 ds_read_b128 = window taps for 4 input channels.
    // Tap d (padded H=2p+d): d even -> F4C(we[d/2]), d odd -> F4C(wo[(d-1)/2]).
    {
        const int g   = __builtin_amdgcn_readfirstlane(tid >> 7);   // 0..7
        const int p   = tid & 127;
        const bool act = p < 87;
        const int pr  = act ? p : 0;
        const float* wb = w2 + g * 4 * 144;   // [oc][ci][kh], oc stride 144

        float a0[4], a1[4];
#pragma unroll
        for (int j = 0; j < 4; ++j) { a0[j] = b2[g*4 + j]; a1[j] = a0[j]; }

#pragma unroll 1
        for (int qd = 0; qd < 4; ++qd) {
            float4 we[5], wo[5];
#pragma unroll
            for (int d = 0; d < 5; ++d) { we[d] = r1qe[qd][pr + d]; wo[d] = r1qo[qd][pr + d]; }

#pragma unroll
            for (int c4 = 0; c4 < 4; ++c4) {
                const int ci = qd * 4 + c4;
#pragma unroll
                for (int j = 0; j < 4; ++j) {
                    const float* wj = wb + j * 144 + ci * 9;
#pragma unroll
                    for (int kh = 0; kh < 9; ++kh) {
                        float wv  = wj[kh];
                        float xlo = (kh & 1) ? F4C(wo[kh >> 1], c4)
                                             : F4C(we[kh >> 1], c4);        // tap kh
                        float xhi = (kh & 1) ? F4C(we[(kh + 1) >> 1], c4)
                                             : F4C(wo[kh >> 1], c4);        // tap kh+1
                        a0[j] += wv * xlo;     // h = 2p
                        a1[j] += wv * xhi;     // h = 2p+1
                    }
                }
            }
        }
        float r3t[4];
#pragma unroll
        for (int j = 0; j < 4; ++j) {
            float r20 = spike_rate(a0[j], ratetbl);
            float r21 = spike_rate(a1[j], ratetbl);
            r3t[j] = spike_rate_nb(1.1f * (r20 + r21), ratetbl);
        }
        if (act) r3q[g][p + 1] = make_float4(r3t[0], r3t[1], r3t[2], r3t[3]);
    }
    __syncthreads();

    // ---- phase 4: conv3 (32->32, k=7, pad=1) + rate ----
    // 16 waves = 8 out-ch-groups(4) x 2 h-halves; lanes -> h.
    // Per ci-quad: 7 ds_read_b128 window taps (4 input channels each).
    {
        const int gg   = __builtin_amdgcn_readfirstlane(wave >> 1);  // 0..7
        const int g4   = gg * 4;
        const int half = wave & 1;
        const int cnt  = half ? 41 : 42;
        const bool act = lane < cnt;
        const int h0   = half * 42 + lane;    // valid max 82; window max 88
        const int hr   = act ? h0 : 0;
        const float* wb = w3 + g4 * 224;      // [oc][ci][kh], oc stride 224

        float a[4];
#pragma unroll
        for (int j = 0; j < 4; ++j) a[j] = b3[g4 + j];

#pragma unroll 1
        for (int q = 0; q < 8; ++q) {
            float4 rv[7];
#pragma unroll
            for (int d = 0; d < 7; ++d) rv[d] = r3q[q][hr + d];

#pragma unroll
            for (int c4 = 0; c4 < 4; ++c4) {
                const int ci = q * 4 + c4;
#pragma unroll
                for (int j = 0; j < 4; ++j) {
                    const float* wj = wb + j * 224 + ci * 7;
#pragma unroll
                    for (int kh = 0; kh < 7; ++kh)
                        a[j] += wj[kh] * F4C(rv[kh], c4);
                }
            }
        }
#pragma unroll
        for (int j = 0; j < 4; ++j) {
            float r = spike_rate(a[j], ratetbl);
            if (act) r4s[g4 + j][h0] = r;
        }
    }
    __syncthreads();

    // ---- phase 5: dense [32*83] -> 4 outputs; 4 waves per output, float4 ----
    {
        const int o = wave >> 2, q = wave & 3;
        const float4* r44 = reinterpret_cast<const float4*>(&r4s[0][0]);
        const float4* wo4 = reinterpret_cast<const float4*>(wf + o * (32 * 83));
        float acc = 0.f;
        for (int j = q * 64 + lane; j < 664; j += 256) {
            float4 rv = r44[j], wv = wo4[j];
            acc += rv.x * wv.x + rv.y * wv.y;
            acc += rv.z * wv.z + rv.w * wv.w;
        }
#pragma unroll
        for (int off = 32; off > 0; off >>= 1)
            acc += __shfl_down(acc, off, 64);
        if (lane == 0) part[wave] = acc;
    }
    __syncthreads();
    if (tid < 4) {
        float s = part[tid*4] + part[tid*4+1] + part[tid*4+2] + part[tid*4+3];
        out[n * 4 + tid] = s + bf[tid];
    }
}

extern "C" void kernel_launch(void* const* d_in, const int* in_sizes, int n_in,
                              void* d_out, int out_size, void* d_ws, size_t ws_size,
                              hipStream_t stream) {
    const float* x  = (const float*)d_in[0];
    const float* w1 = (const float*)d_in[1];
    const float* b1 = (const float*)d_in[2];
    const float* w2 = (const float*)d_in[3];
    const float* b2 = (const float*)d_in[4];
    const float* w3 = (const float*)d_in[5];
    const float* b3 = (const float*)d_in[6];
    const float* wf = (const float*)d_in[7];
    const float* bf = (const float*)d_in[8];
    float* outp = (float*)d_out;

    catnet_kernel<<<dim3(256), dim3(1024), 0, stream>>>(
        x, w1, b1, w2, b2, w3, b3, wf, bf, outp);
}